// Round 1
// baseline (197.881 us; speedup 1.0000x reference)
//
#include <hip/hip_runtime.h>
#include <hip/hip_bf16.h>
#include <stdint.h>

#define N_TOT 8192
#define BHALF 4096
#define DIM   256
#define TEMP_INV 2.0f

typedef short s8v __attribute__((ext_vector_type(8)));   // 8 bf16 in 4 VGPRs
typedef float f4v __attribute__((ext_vector_type(4)));   // MFMA accumulator

static __device__ __forceinline__ unsigned short f2bf(float f) {
    union { float f; uint32_t u; } v; v.f = f;
    uint32_t r = (v.u + 0x7FFFu + ((v.u >> 16) & 1u)) >> 16;  // RNE
    return (unsigned short)r;
}

// K1: L2-normalize rows of concat(z_i, z_j) -> bf16 zb[8192][256]
__global__ __launch_bounds__(256) void nrm_kernel(const float* __restrict__ zi,
                                                  const float* __restrict__ zj,
                                                  unsigned short* __restrict__ zb) {
    const int row  = blockIdx.x * 4 + (threadIdx.x >> 6);
    const int lane = threadIdx.x & 63;
    const float* src = (row < BHALF) ? (zi + (size_t)row * DIM)
                                     : (zj + (size_t)(row - BHALF) * DIM);
    float4 v = *(const float4*)(src + lane * 4);
    float s = v.x*v.x + v.y*v.y + v.z*v.z + v.w*v.w;
    #pragma unroll
    for (int off = 1; off < 64; off <<= 1) s += __shfl_xor(s, off, 64);
    float inv = 1.0f / fmaxf(sqrtf(s), 1e-12f);
    ushort4 o;
    o.x = f2bf(v.x * inv); o.y = f2bf(v.y * inv);
    o.z = f2bf(v.z * inv); o.w = f2bf(v.w * inv);
    *(ushort4*)(zb + (size_t)row * DIM + lane * 4) = o;
}

// K2: fused sim + exp-sum + label capture.
// Grid: 1024 blocks = 256 row-groups (32 rows) x 4 col-groups (2048 cols).
// Wave: 32 rows x 512 cols. A-frags register-resident, B-frags streamed from L2.
__global__ __launch_bounds__(256) void sim_kernel(const unsigned short* __restrict__ zb,
                                                  float* __restrict__ sumexp,
                                                  float* __restrict__ labsim) {
    const int lane = threadIdx.x & 63;
    const int wave = threadIdx.x >> 6;
    const int rb   = blockIdx.x >> 2;
    const int cbg  = blockIdx.x & 3;
    const int row_base  = rb * 32;
    const int wcol_base = cbg * 2048 + wave * 512;
    const int l15  = lane & 15;
    const int quad = lane >> 4;

    // A fragments: A[m=lane&15][k=quad*8+j], m in two 16-row tiles. 64 VGPRs.
    s8v a[2][8];
    #pragma unroll
    for (int rt = 0; rt < 2; ++rt) {
        const unsigned short* ap = zb + (size_t)(row_base + rt*16 + l15) * DIM + quad * 8;
        #pragma unroll
        for (int ks = 0; ks < 8; ++ks)
            a[rt][ks] = *(const s8v*)(ap + ks * 32);
    }

    float se[2][4] = {{0.f,0.f,0.f,0.f},{0.f,0.f,0.f,0.f}};
    float ls[2][4] = {{0.f,0.f,0.f,0.f},{0.f,0.f,0.f,0.f}};

    for (int ct = 0; ct < 32; ++ct) {
        const int c0 = wcol_base + ct * 16;
        // B fragments: B[k][n=lane&15], k=quad*8+j (same pattern as A: ZZ^T)
        const unsigned short* bp = zb + (size_t)(c0 + l15) * DIM + quad * 8;
        s8v b[8];
        #pragma unroll
        for (int ks = 0; ks < 8; ++ks) b[ks] = *(const s8v*)(bp + ks * 32);

        f4v acc[2];
        acc[0] = (f4v){0.f,0.f,0.f,0.f};
        acc[1] = (f4v){0.f,0.f,0.f,0.f};
        #pragma unroll
        for (int ks = 0; ks < 8; ++ks) {
            acc[0] = __builtin_amdgcn_mfma_f32_16x16x32_bf16(a[0][ks], b[ks], acc[0], 0, 0, 0);
            acc[1] = __builtin_amdgcn_mfma_f32_16x16x32_bf16(a[1][ks], b[ks], acc[1], 0, 0, 0);
        }

        const int col = c0 + l15;  // C/D: col=lane&15, row=quad*4+reg
        #pragma unroll
        for (int rt = 0; rt < 2; ++rt) {
            #pragma unroll
            for (int r = 0; r < 4; ++r) {
                const int row = row_base + rt*16 + quad*4 + r;
                const float sim = acc[rt][r] * TEMP_INV;
                const float e = __expf(sim);
                se[rt][r] += (row == col) ? 0.f : e;           // diag -> NEG_FILL -> exp=0
                const int lbl = (row < BHALF) ? row + BHALF : row - BHALF;
                ls[rt][r] += (col == lbl) ? sim : 0.f;
            }
        }
    }

    // reduce across the 16 lanes of each quad (same rows, different cols)
    #pragma unroll
    for (int rt = 0; rt < 2; ++rt) {
        #pragma unroll
        for (int r = 0; r < 4; ++r) {
            float s = se[rt][r], l = ls[rt][r];
            #pragma unroll
            for (int off = 1; off < 16; off <<= 1) {
                s += __shfl_xor(s, off, 64);
                l += __shfl_xor(l, off, 64);
            }
            se[rt][r] = s; ls[rt][r] = l;
        }
    }
    if (l15 == 0) {
        #pragma unroll
        for (int rt = 0; rt < 2; ++rt) {
            #pragma unroll
            for (int r = 0; r < 4; ++r) {
                const int row = row_base + rt*16 + quad*4 + r;
                atomicAdd(&sumexp[row], se[rt][r]);
                atomicAdd(&labsim[row], ls[rt][r]);
            }
        }
    }
}

// K3: loss = mean(log(sumexp) - labsim)
__global__ __launch_bounds__(256) void fin_kernel(const float* __restrict__ sumexp,
                                                  const float* __restrict__ labsim,
                                                  float* __restrict__ out) {
    const int tid = threadIdx.x;
    float acc = 0.f;
    for (int i = tid; i < N_TOT; i += 256)
        acc += logf(sumexp[i]) - labsim[i];
    #pragma unroll
    for (int off = 1; off < 64; off <<= 1) acc += __shfl_xor(acc, off, 64);
    __shared__ float wsum[4];
    if ((tid & 63) == 0) wsum[tid >> 6] = acc;
    __syncthreads();
    if (tid == 0) out[0] = (wsum[0] + wsum[1] + wsum[2] + wsum[3]) / (float)N_TOT;
}

extern "C" void kernel_launch(void* const* d_in, const int* in_sizes, int n_in,
                              void* d_out, int out_size, void* d_ws, size_t ws_size,
                              hipStream_t stream) {
    const float* zi = (const float*)d_in[0];
    const float* zj = (const float*)d_in[1];
    unsigned short* zb = (unsigned short*)d_ws;                       // 4 MB bf16
    float* sumexp = (float*)((char*)d_ws + (size_t)N_TOT * DIM * 2);  // 32 KB
    float* labsim = sumexp + N_TOT;                                   // 32 KB

    hipMemsetAsync(sumexp, 0, 2 * N_TOT * sizeof(float), stream);
    nrm_kernel<<<N_TOT / 4, 256, 0, stream>>>(zi, zj, zb);
    sim_kernel<<<1024, 256, 0, stream>>>(zb, sumexp, labsim);
    fin_kernel<<<1, 256, 0, stream>>>(sumexp, labsim, (float*)d_out);
}

// Round 2
// 143.379 us; speedup vs baseline: 1.3801x; 1.3801x over previous
//
#include <hip/hip_runtime.h>
#include <hip/hip_bf16.h>
#include <stdint.h>

#define N_TOT 8192
#define BHALF 4096
#define DIM   256
#define E2    7.38905609893065f   // exp(2): diag term, subtracted in fin

typedef short s8v __attribute__((ext_vector_type(8)));   // 8 bf16 in 4 VGPRs
typedef float f4v __attribute__((ext_vector_type(4)));   // MFMA accumulator

static __device__ __forceinline__ unsigned short f2bf(float f) {
    union { float f; uint32_t u; } v; v.f = f;
    uint32_t r = (v.u + 0x7FFFu + ((v.u >> 16) & 1u)) >> 16;  // RNE
    return (unsigned short)r;
}

// K1: normalize pair rows (p from z_i, p+4096 from z_j), emit bf16 zb,
// compute label sim 2*dot(zhat_p, zhat_q) in fp32, zero sumexp slice.
__global__ __launch_bounds__(256) void nrm_kernel(const float* __restrict__ zi,
                                                  const float* __restrict__ zj,
                                                  unsigned short* __restrict__ zb,
                                                  float* __restrict__ sumexp,
                                                  float* __restrict__ lab2) {
    const int wave = threadIdx.x >> 6;
    const int lane = threadIdx.x & 63;
    const int half = lane >> 5;          // 0: row p, 1: row p+4096
    const int sl   = lane & 31;
    const int p    = blockIdx.x * 4 + wave;
    const int row  = half ? (p + BHALF) : p;
    const float* src = (half ? zj : zi) + (size_t)p * DIM;

    float4 v0 = *(const float4*)(src + sl * 8);
    float4 v1 = *(const float4*)(src + sl * 8 + 4);
    float s = v0.x*v0.x + v0.y*v0.y + v0.z*v0.z + v0.w*v0.w
            + v1.x*v1.x + v1.y*v1.y + v1.z*v1.z + v1.w*v1.w;
    #pragma unroll
    for (int m = 1; m < 32; m <<= 1) s += __shfl_xor(s, m, 64);  // within half
    const float inv = 1.0f / fmaxf(sqrtf(s), 1e-12f);

    float n[8] = { v0.x*inv, v0.y*inv, v0.z*inv, v0.w*inv,
                   v1.x*inv, v1.y*inv, v1.z*inv, v1.w*inv };
    // bf16 store (16B/lane)
    union { s8v v; unsigned short u[8]; } o;
    #pragma unroll
    for (int j = 0; j < 8; ++j) o.u[j] = f2bf(n[j]);
    *(s8v*)(zb + (size_t)row * DIM + sl * 8) = o.v;

    // cross dot with partner half (fp32, pre-bf16 — closest to reference)
    float d = 0.f;
    #pragma unroll
    for (int j = 0; j < 8; ++j) d += n[j] * __shfl_xor(n[j], 32, 64);
    #pragma unroll
    for (int m = 1; m < 32; m <<= 1) d += __shfl_xor(d, m, 64);
    if (lane == 0) lab2[p] = 2.0f * d;   // sim value = dot / 0.5

    // zero sumexp (8 floats per block * 1024 blocks = 8192)
    if (threadIdx.x < 8) sumexp[blockIdx.x * 8 + threadIdx.x] = 0.f;
}

// K2: sim + exp-sum. Grid 512 = 32 row-blocks(256) x 16 col-blocks(512).
// Wave: 64 rows x 512 cols. A register-resident; B register double-buffered.
__global__ __launch_bounds__(256, 2) void sim_kernel(const unsigned short* __restrict__ zb,
                                                     float* __restrict__ sumexp) {
    const int lane = threadIdx.x & 63;
    const int wave = threadIdx.x >> 6;
    const int rb   = blockIdx.x >> 4;
    const int cb   = blockIdx.x & 15;
    const int row0 = rb * 256 + wave * 64;
    const int col_base = cb * 512;
    const int l15  = lane & 15;
    const int quad = lane >> 4;

    // A fragments: A[m=l15][k=quad*8+j], 4 row-tiles of 16. 128 VGPRs.
    s8v a[4][8];
    #pragma unroll
    for (int rt = 0; rt < 4; ++rt) {
        const unsigned short* ap = zb + (size_t)(row0 + rt*16 + l15) * DIM + quad * 8;
        #pragma unroll
        for (int ks = 0; ks < 8; ++ks) a[rt][ks] = *(const s8v*)(ap + ks * 32);
    }

    s8v b0[8], b1[8];
    {
        const unsigned short* bp = zb + (size_t)(col_base + l15) * DIM + quad * 8;
        #pragma unroll
        for (int ks = 0; ks < 8; ++ks) b0[ks] = *(const s8v*)(bp + ks * 32);
    }

    float se[4][4];
    #pragma unroll
    for (int rt = 0; rt < 4; ++rt)
        #pragma unroll
        for (int r = 0; r < 4; ++r) se[rt][r] = 0.f;

#define SIM_BODY(BCUR, BNXT, CT)                                                   \
    {                                                                              \
        const int nc = col_base + (((CT) + 1) & 31) * 16;                          \
        const unsigned short* np = zb + (size_t)(nc + l15) * DIM + quad * 8;       \
        _Pragma("unroll")                                                          \
        for (int ks = 0; ks < 8; ++ks) BNXT[ks] = *(const s8v*)(np + ks * 32);     \
        f4v acc[4];                                                                \
        _Pragma("unroll")                                                          \
        for (int rt = 0; rt < 4; ++rt) acc[rt] = (f4v){0.f, 0.f, 0.f, 0.f};       \
        _Pragma("unroll")                                                          \
        for (int ks = 0; ks < 8; ++ks) {                                           \
            _Pragma("unroll")                                                      \
            for (int rt = 0; rt < 4; ++rt)                                         \
                acc[rt] = __builtin_amdgcn_mfma_f32_16x16x32_bf16(                 \
                    a[rt][ks], BCUR[ks], acc[rt], 0, 0, 0);                        \
        }                                                                          \
        _Pragma("unroll")                                                          \
        for (int rt = 0; rt < 4; ++rt)                                             \
            _Pragma("unroll")                                                      \
            for (int r = 0; r < 4; ++r)                                            \
                se[rt][r] += __expf(acc[rt][r] * 2.0f);                            \
    }

    #pragma unroll 1
    for (int ct = 0; ct < 32; ct += 2) {
        SIM_BODY(b0, b1, ct)
        SIM_BODY(b1, b0, ct + 1)
    }
#undef SIM_BODY

    // reduce over the 16 lanes of each quad (same rows, different cols)
    #pragma unroll
    for (int rt = 0; rt < 4; ++rt) {
        #pragma unroll
        for (int r = 0; r < 4; ++r) {
            float s = se[rt][r];
            #pragma unroll
            for (int m = 1; m < 16; m <<= 1) s += __shfl_xor(s, m, 64);
            if (l15 == 0)
                atomicAdd(&sumexp[row0 + rt*16 + quad*4 + r], s);
        }
    }
}

// K3: loss = mean_i( log(sumexp_i - e^2) ) - mean_i( sim_{i,label} )
__global__ __launch_bounds__(256) void fin_kernel(const float* __restrict__ sumexp,
                                                  const float* __restrict__ lab2,
                                                  float* __restrict__ out) {
    const int tid = threadIdx.x;
    float acc = 0.f;
    for (int i = tid; i < N_TOT; i += 256)
        acc += logf(sumexp[i] - E2);
    for (int p = tid; p < BHALF; p += 256)
        acc -= 2.0f * lab2[p];    // each pair's sim counts for both rows
    #pragma unroll
    for (int m = 1; m < 64; m <<= 1) acc += __shfl_xor(acc, m, 64);
    __shared__ float wsum[4];
    if ((tid & 63) == 0) wsum[tid >> 6] = acc;
    __syncthreads();
    if (tid == 0) out[0] = (wsum[0] + wsum[1] + wsum[2] + wsum[3]) / (float)N_TOT;
}

extern "C" void kernel_launch(void* const* d_in, const int* in_sizes, int n_in,
                              void* d_out, int out_size, void* d_ws, size_t ws_size,
                              hipStream_t stream) {
    const float* zi = (const float*)d_in[0];
    const float* zj = (const float*)d_in[1];
    unsigned short* zb = (unsigned short*)d_ws;                        // 4 MB bf16
    float* sumexp = (float*)((char*)d_ws + (size_t)N_TOT * DIM * 2);   // 32 KB
    float* lab2   = sumexp + N_TOT;                                    // 16 KB

    nrm_kernel<<<1024, 256, 0, stream>>>(zi, zj, zb, sumexp, lab2);
    sim_kernel<<<512, 256, 0, stream>>>(zb, sumexp);
    fin_kernel<<<1, 256, 0, stream>>>(sumexp, lab2, (float*)d_out);
}

// Round 4
// 112.060 us; speedup vs baseline: 1.7658x; 1.2795x over previous
//
#include <hip/hip_runtime.h>
#include <hip/hip_bf16.h>
#include <stdint.h>

#define N_TOT 8192
#define BHALF 4096
#define DIM   256
#define E2     7.38905609893065f    // exp(2): diag term, subtracted in fin
#define LOG2E2 2.8853900817779268f  // 2*log2(e): exp(2x) = exp2(x*LOG2E2)

typedef short s8v __attribute__((ext_vector_type(8)));   // 8 bf16 in 4 VGPRs
typedef float f4v __attribute__((ext_vector_type(4)));   // MFMA accumulator
typedef __attribute__((address_space(1))) void gvoid;
typedef __attribute__((address_space(3))) void svoid;

static __device__ __forceinline__ unsigned short f2bf(float f) {
    union { float f; uint32_t u; } v; v.f = f;
    uint32_t r = (v.u + 0x7FFFu + ((v.u >> 16) & 1u)) >> 16;  // RNE
    return (unsigned short)r;
}

// K1: normalize pair rows (p from z_i, p+4096 from z_j), emit bf16 zb,
// compute label sim 2*dot in fp32, zero sumexp slice.
__global__ __launch_bounds__(256) void nrm_kernel(const float* __restrict__ zi,
                                                  const float* __restrict__ zj,
                                                  unsigned short* __restrict__ zb,
                                                  float* __restrict__ sumexp,
                                                  float* __restrict__ lab2) {
    const int wave = threadIdx.x >> 6;
    const int lane = threadIdx.x & 63;
    const int half = lane >> 5;          // 0: row p, 1: row p+4096
    const int sl   = lane & 31;
    const int p    = blockIdx.x * 4 + wave;
    const int row  = half ? (p + BHALF) : p;
    const float* src = (half ? zj : zi) + (size_t)p * DIM;

    float4 v0 = *(const float4*)(src + sl * 8);
    float4 v1 = *(const float4*)(src + sl * 8 + 4);
    float s = v0.x*v0.x + v0.y*v0.y + v0.z*v0.z + v0.w*v0.w
            + v1.x*v1.x + v1.y*v1.y + v1.z*v1.z + v1.w*v1.w;
    #pragma unroll
    for (int m = 1; m < 32; m <<= 1) s += __shfl_xor(s, m, 64);  // within half
    const float inv = 1.0f / fmaxf(sqrtf(s), 1e-12f);

    float n[8] = { v0.x*inv, v0.y*inv, v0.z*inv, v0.w*inv,
                   v1.x*inv, v1.y*inv, v1.z*inv, v1.w*inv };
    union { s8v v; unsigned short u[8]; } o;
    #pragma unroll
    for (int j = 0; j < 8; ++j) o.u[j] = f2bf(n[j]);
    *(s8v*)(zb + (size_t)row * DIM + sl * 8) = o.v;

    float d = 0.f;
    #pragma unroll
    for (int j = 0; j < 8; ++j) d += n[j] * __shfl_xor(n[j], 32, 64);
    #pragma unroll
    for (int m = 1; m < 32; m <<= 1) d += __shfl_xor(d, m, 64);
    if (lane == 0) lab2[p] = 2.0f * d;

    if (threadIdx.x < 8) sumexp[blockIdx.x * 8 + threadIdx.x] = 0.f;
}

// K2: sim + exp-sum. Grid 512 = 32 row-blocks(256 rows) x 16 col-blocks(512 cols).
// Wave: 64 rows (A register-resident, asm-pinned). B: LDS double-buffered,
// K-major tiles of 32 cols staged via global_load_lds(16B), shared by 4 waves.
__global__ __launch_bounds__(256, 2) void sim_kernel(const unsigned short* __restrict__ zb,
                                                     float* __restrict__ sumexp) {
    __shared__ s8v tile[2][1024];   // 2 x 16KB; granule (k16, c): idx = k16*32 + c
    const int lane = threadIdx.x & 63;
    const int wave = threadIdx.x >> 6;
    const int rb   = blockIdx.x >> 4;
    const int cb   = blockIdx.x & 15;
    const int row0 = rb * 256 + wave * 64;
    const int col0 = cb * 512;
    const int l15  = lane & 15;
    const int quad = lane >> 4;

    // A fragments: A[m=l15][k=quad*8+j], 4 row-tiles of 16 -> 128 VGPRs.
    s8v a[4][8];
    #pragma unroll
    for (int rt = 0; rt < 4; ++rt) {
        const unsigned short* ap = zb + (size_t)(row0 + rt*16 + l15) * DIM + quad * 8;
        #pragma unroll
        for (int ks = 0; ks < 8; ++ks) a[rt][ks] = *(const s8v*)(ap + ks * 32);
    }
    // Pin A in VGPRs: opaque asm prevents the compiler from re-loading per iter
    // (round-2 VGPR_Count=100 proved it rematerializes otherwise).
    #pragma unroll
    for (int rt = 0; rt < 4; ++rt)
        #pragma unroll
        for (int ks = 0; ks < 8; ++ks)
            asm volatile("" : "+v"(a[rt][ks]));

    float se[4][4];
    #pragma unroll
    for (int rt = 0; rt < 4; ++rt)
        #pragma unroll
        for (int r = 0; r < 4; ++r) se[rt][r] = 0.f;

    // Stage 32 cols (16KB) into tile[BUF], K-major: lds granule g -> col (g&31),
    // k16 (g>>5). Per wave 4 issues of 64 lanes x 16B.
#define STAGE(BUF, CT)                                                              \
    {                                                                               \
        _Pragma("unroll")                                                           \
        for (int j = 0; j < 4; ++j) {                                               \
            const int g = (wave * 4 + j) * 64 + lane;                               \
            const unsigned short* gp = zb + (size_t)(col0 + (CT)*32 + (g & 31))*DIM \
                                          + (g >> 5) * 8;                           \
            __builtin_amdgcn_global_load_lds((gvoid*)gp,                            \
                (svoid*)&tile[BUF][(wave * 4 + j) * 64], 16, 0, 0);                 \
        }                                                                           \
    }

#define COMPUTE(BUF)                                                                \
    {                                                                               \
        _Pragma("unroll")                                                           \
        for (int ct2 = 0; ct2 < 2; ++ct2) {                                         \
            s8v b[8];                                                               \
            _Pragma("unroll")                                                       \
            for (int ks = 0; ks < 8; ++ks)                                          \
                b[ks] = tile[BUF][(quad + 4*ks) * 32 + ct2*16 + l15];               \
            f4v acc[4];                                                             \
            _Pragma("unroll")                                                       \
            for (int rt = 0; rt < 4; ++rt) acc[rt] = (f4v){0.f, 0.f, 0.f, 0.f};    \
            _Pragma("unroll")                                                       \
            for (int ks = 0; ks < 8; ++ks) {                                        \
                _Pragma("unroll")                                                   \
                for (int rt = 0; rt < 4; ++rt)                                      \
                    acc[rt] = __builtin_amdgcn_mfma_f32_16x16x32_bf16(              \
                        a[rt][ks], b[ks], acc[rt], 0, 0, 0);                        \
            }                                                                       \
            _Pragma("unroll")                                                       \
            for (int rt = 0; rt < 4; ++rt)                                          \
                _Pragma("unroll")                                                   \
                for (int r = 0; r < 4; ++r)                                         \
                    se[rt][r] += __builtin_amdgcn_exp2f(acc[rt][r] * LOG2E2);       \
        }                                                                           \
    }

    STAGE(0, 0)
    __syncthreads();
    #pragma unroll 1
    for (int it = 0; it < 16; ++it) {
        const int buf = it & 1;
        if (it < 15) STAGE(buf ^ 1, it + 1)
        COMPUTE(buf)
        __syncthreads();
    }
#undef STAGE
#undef COMPUTE

    // reduce over the 16 lanes of each quad (same rows, different cols)
    #pragma unroll
    for (int rt = 0; rt < 4; ++rt) {
        #pragma unroll
        for (int r = 0; r < 4; ++r) {
            float s = se[rt][r];
            #pragma unroll
            for (int m = 1; m < 16; m <<= 1) s += __shfl_xor(s, m, 64);
            if (l15 == 0)
                atomicAdd(&sumexp[row0 + rt*16 + quad*4 + r], s);
        }
    }
}

// K3: loss = mean_i( log(sumexp_i - e^2) ) - mean_i( sim_{i,label} )
__global__ __launch_bounds__(256) void fin_kernel(const float* __restrict__ sumexp,
                                                  const float* __restrict__ lab2,
                                                  float* __restrict__ out) {
    const int tid = threadIdx.x;
    float acc = 0.f;
    for (int i = tid; i < N_TOT; i += 256)
        acc += logf(sumexp[i] - E2);
    for (int p = tid; p < BHALF; p += 256)
        acc -= 2.0f * lab2[p];
    #pragma unroll
    for (int m = 1; m < 64; m <<= 1) acc += __shfl_xor(acc, m, 64);
    __shared__ float wsum[4];
    if ((tid & 63) == 0) wsum[tid >> 6] = acc;
    __syncthreads();
    if (tid == 0) out[0] = (wsum[0] + wsum[1] + wsum[2] + wsum[3]) / (float)N_TOT;
}

extern "C" void kernel_launch(void* const* d_in, const int* in_sizes, int n_in,
                              void* d_out, int out_size, void* d_ws, size_t ws_size,
                              hipStream_t stream) {
    const float* zi = (const float*)d_in[0];
    const float* zj = (const float*)d_in[1];
    unsigned short* zb = (unsigned short*)d_ws;                        // 4 MB bf16
    float* sumexp = (float*)((char*)d_ws + (size_t)N_TOT * DIM * 2);   // 32 KB
    float* lab2   = sumexp + N_TOT;                                    // 16 KB

    nrm_kernel<<<1024, 256, 0, stream>>>(zi, zj, zb, sumexp, lab2);
    sim_kernel<<<512, 256, 0, stream>>>(zb, sumexp);
    fin_kernel<<<1, 256, 0, stream>>>(sumexp, lab2, (float*)d_out);
}

// Round 5
// 111.549 us; speedup vs baseline: 1.7739x; 1.0046x over previous
//
#include <hip/hip_runtime.h>
#include <hip/hip_bf16.h>
#include <stdint.h>

#define N_TOT 8192
#define BHALF 4096
#define DIM   256
#define E2     7.38905609893065f    // exp(2): diag term, subtracted in fin
#define LOG2E2 2.8853900817779268f  // 2*log2(e): exp(2x) = exp2(x*LOG2E2)

typedef short s8v __attribute__((ext_vector_type(8)));   // 8 bf16 in 4 VGPRs
typedef float f4v __attribute__((ext_vector_type(4)));   // MFMA accumulator

static __device__ __forceinline__ unsigned short f2bf(float f) {
    union { float f; uint32_t u; } v; v.f = f;
    uint32_t r = (v.u + 0x7FFFu + ((v.u >> 16) & 1u)) >> 16;  // RNE
    return (unsigned short)r;
}

// Fragment-major layout: granule g = (row>>4)*8 + (k8>>2), lane = (row&15) + 16*(k8&3),
// where k8 = k/8. zbF[g*64 + lane] is one s8v (16B = 8 bf16, k = k8*8..+8).
// A wave's MFMA fragment (16 rows x 32 k) == one contiguous 2KB granule, lane-ordered
// => every A/B fragment load is a single coalesced contiguous 1KB wave-load.

// K1: normalize pair rows (p from z_i, p+4096 from z_j), emit fragment-major bf16,
// compute label sim 2*dot in fp32, zero sumexp slice.
__global__ __launch_bounds__(256) void nrm_kernel(const float* __restrict__ zi,
                                                  const float* __restrict__ zj,
                                                  s8v* __restrict__ zbF,
                                                  float* __restrict__ sumexp,
                                                  float* __restrict__ lab2) {
    const int wave = threadIdx.x >> 6;
    const int lane = threadIdx.x & 63;
    const int half = lane >> 5;          // 0: row p, 1: row p+4096
    const int sl   = lane & 31;          // k8 chunk index (8 elems each)
    const int p    = blockIdx.x * 4 + wave;
    const int row  = half ? (p + BHALF) : p;
    const float* src = (half ? zj : zi) + (size_t)p * DIM;

    float4 v0 = *(const float4*)(src + sl * 8);
    float4 v1 = *(const float4*)(src + sl * 8 + 4);
    float s = v0.x*v0.x + v0.y*v0.y + v0.z*v0.z + v0.w*v0.w
            + v1.x*v1.x + v1.y*v1.y + v1.z*v1.z + v1.w*v1.w;
    #pragma unroll
    for (int m = 1; m < 32; m <<= 1) s += __shfl_xor(s, m, 64);  // within half
    const float inv = 1.0f / fmaxf(sqrtf(s), 1e-12f);

    float n[8] = { v0.x*inv, v0.y*inv, v0.z*inv, v0.w*inv,
                   v1.x*inv, v1.y*inv, v1.z*inv, v1.w*inv };
    union { s8v v; unsigned short u[8]; } o;
    #pragma unroll
    for (int j = 0; j < 8; ++j) o.u[j] = f2bf(n[j]);
    // fragment-major store: k8 = sl
    zbF[(size_t)(((row >> 4) * 8 + (sl >> 2)) * 64) + (row & 15) + 16 * (sl & 3)] = o.v;

    float d = 0.f;
    #pragma unroll
    for (int j = 0; j < 8; ++j) d += n[j] * __shfl_xor(n[j], 32, 64);
    #pragma unroll
    for (int m = 1; m < 32; m <<= 1) d += __shfl_xor(d, m, 64);
    if (lane == 0) lab2[p] = 2.0f * d;

    if (threadIdx.x < 8) sumexp[blockIdx.x * 8 + threadIdx.x] = 0.f;
}

// K2: sim + exp-sum, barrier-free streaming. Grid 512 = 32 row-blocks x 16 col-blocks.
// Wave: 64 rows (A register-resident, asm-pinned) x 512 cols streamed from L2 with
// register-double-buffered B fragments. No LDS, no __syncthreads — the compiler is
// free to schedule loads with fine-grained vmcnt (the AITER pattern).
__global__ __launch_bounds__(256, 2) void sim_kernel(const s8v* __restrict__ zbF,
                                                     float* __restrict__ sumexp) {
    const int lane = threadIdx.x & 63;
    const int wave = threadIdx.x >> 6;
    const int rb   = blockIdx.x >> 4;
    const int cb   = blockIdx.x & 15;
    const int row0 = rb * 256 + wave * 64;
    const int ct0  = cb * 32;            // base col-tile (16-col units)
    const int l15  = lane & 15;
    const int quad = lane >> 4;

    // A fragments: 4 row-tiles x 8 k-chunks, each one contiguous granule. 128 VGPRs.
    s8v a[4][8];
    #pragma unroll
    for (int rt = 0; rt < 4; ++rt) {
        const s8v* ap = zbF + (size_t)(((row0 >> 4) + rt) * 8) * 64 + lane;
        #pragma unroll
        for (int c = 0; c < 8; ++c) a[rt][c] = ap[c * 64];
    }
    // Pin A in VGPRs (R2's VGPR=100 proved the compiler re-loads otherwise).
    #pragma unroll
    for (int rt = 0; rt < 4; ++rt)
        #pragma unroll
        for (int c = 0; c < 8; ++c)
            asm volatile("" : "+v"(a[rt][c]));

    float se[4][4];
    #pragma unroll
    for (int rt = 0; rt < 4; ++rt)
        #pragma unroll
        for (int r = 0; r < 4; ++r) se[rt][r] = 0.f;

    s8v b0[8], b1[8];
    {
        const s8v* bp = zbF + (size_t)(ct0 * 8) * 64 + lane;
        #pragma unroll
        for (int c = 0; c < 8; ++c) b0[c] = bp[c * 64];
    }

#define SIM_BODY(BCUR, BNXT, CT)                                                   \
    {                                                                              \
        const s8v* np = zbF + (size_t)((ct0 + (((CT) + 1) & 31)) * 8) * 64 + lane; \
        _Pragma("unroll")                                                          \
        for (int c = 0; c < 8; ++c) BNXT[c] = np[c * 64];                          \
        f4v acc[4];                                                                \
        _Pragma("unroll")                                                          \
        for (int rt = 0; rt < 4; ++rt) acc[rt] = (f4v){0.f, 0.f, 0.f, 0.f};       \
        _Pragma("unroll")                                                          \
        for (int c = 0; c < 8; ++c) {                                              \
            _Pragma("unroll")                                                      \
            for (int rt = 0; rt < 4; ++rt)                                         \
                acc[rt] = __builtin_amdgcn_mfma_f32_16x16x32_bf16(                 \
                    a[rt][c], BCUR[c], acc[rt], 0, 0, 0);                          \
        }                                                                          \
        _Pragma("unroll")                                                          \
        for (int rt = 0; rt < 4; ++rt)                                             \
            _Pragma("unroll")                                                      \
            for (int r = 0; r < 4; ++r)                                            \
                se[rt][r] += __builtin_amdgcn_exp2f(acc[rt][r] * LOG2E2);          \
    }

    #pragma unroll 1
    for (int ct = 0; ct < 32; ct += 2) {
        SIM_BODY(b0, b1, ct)
        SIM_BODY(b1, b0, ct + 1)
    }
#undef SIM_BODY

    // reduce over the 16 lanes of each quad (same rows, different cols)
    #pragma unroll
    for (int rt = 0; rt < 4; ++rt) {
        #pragma unroll
        for (int r = 0; r < 4; ++r) {
            float s = se[rt][r];
            #pragma unroll
            for (int m = 1; m < 16; m <<= 1) s += __shfl_xor(s, m, 64);
            if (l15 == 0)
                atomicAdd(&sumexp[row0 + rt*16 + quad*4 + r], s);
        }
    }
}

// K3: loss = mean_i( log(sumexp_i - e^2) ) - mean_i( sim_{i,label} )
__global__ __launch_bounds__(256) void fin_kernel(const float* __restrict__ sumexp,
                                                  const float* __restrict__ lab2,
                                                  float* __restrict__ out) {
    const int tid = threadIdx.x;
    float acc = 0.f;
    for (int i = tid; i < N_TOT; i += 256)
        acc += logf(sumexp[i] - E2);
    for (int p = tid; p < BHALF; p += 256)
        acc -= 2.0f * lab2[p];
    #pragma unroll
    for (int m = 1; m < 64; m <<= 1) acc += __shfl_xor(acc, m, 64);
    __shared__ float wsum[4];
    if ((tid & 63) == 0) wsum[tid >> 6] = acc;
    __syncthreads();
    if (tid == 0) out[0] = (wsum[0] + wsum[1] + wsum[2] + wsum[3]) / (float)N_TOT;
}

extern "C" void kernel_launch(void* const* d_in, const int* in_sizes, int n_in,
                              void* d_out, int out_size, void* d_ws, size_t ws_size,
                              hipStream_t stream) {
    const float* zi = (const float*)d_in[0];
    const float* zj = (const float*)d_in[1];
    s8v* zbF = (s8v*)d_ws;                                             // 4 MB bf16
    float* sumexp = (float*)((char*)d_ws + (size_t)N_TOT * DIM * 2);   // 32 KB
    float* lab2   = sumexp + N_TOT;                                    // 16 KB

    nrm_kernel<<<1024, 256, 0, stream>>>(zi, zj, zbF, sumexp, lab2);
    sim_kernel<<<512, 256, 0, stream>>>(zbF, sumexp);
    fin_kernel<<<1, 256, 0, stream>>>(sumexp, lab2, (float*)d_out);
}